// Round 10
// baseline (2291.864 us; speedup 1.0000x reference)
//
#include <hip/hip_runtime.h>
#include <hip/hip_bf16.h>

typedef unsigned short u16;
typedef __attribute__((ext_vector_type(8))) short bf16x8;
typedef __attribute__((ext_vector_type(8))) u16   u16x8;
typedef __attribute__((ext_vector_type(4))) float f32x4;

#define T_STEPS 256
#define BATCH   128
#define INDIM   512
#define HDIM    1024
#define GDIM    4096
#define KTOT    1536

#define OFF_XBF   ((size_t)0)
#define XBF_BYTES ((size_t)T_STEPS * BATCH * INDIM * 2)   // 33554432 (fragment-order)
#define OFF_BM    (OFF_XBF + XBF_BYTES)
#define BM_BYTES  ((size_t)2 * GDIM * KTOT * 2)           // 25165824
#define OFF_BIAS  (OFF_BM + BM_BYTES)
#define BIAS_BYTES ((size_t)2 * GDIM * 4)                 // 32768
#define OFF_CNT   (OFF_BIAS + BIAS_BYTES)
#define OFF_ROLL  (OFF_CNT + 8192)
#define ROLL_BYTES ((size_t)(T_STEPS + 1) * 2 * BATCH * HDIM * 2)  // 134742016
#define WS_NEED   (OFF_ROLL + ROLL_BYTES)

__device__ __forceinline__ u16 f2b(float f) {
  __hip_bfloat16 h = __float2bfloat16(f);
  return *reinterpret_cast<u16*>(&h);
}

// async global->LDS, 16B per lane (dest = wave-uniform base + lane*16)
__device__ __forceinline__ void glds16(const void* g, void* l) {
  __builtin_amdgcn_global_load_lds(
      (const __attribute__((address_space(1))) unsigned int*)g,
      (__attribute__((address_space(3))) unsigned int*)l, 16, 0, 0);
}

// ---------------- prepass: shuffle x (f32) into bf16 MFMA-fragment order ----
// xs[t][q][kq][ks][mi][lane][8 bf16]: per (t,q) tile 32KB; a wave's fragment
// load is one fully-coalesced 1KB burst.
__global__ void k_cast_x(const float* __restrict__ x, u16* __restrict__ xs) {
  int i = blockIdx.x * 256 + threadIdx.x;      // one 8-elem fragment per thread
  int t   = i >> 13;                           // 8192 frags per t
  int r13 = i & 8191;
  int row = r13 >> 6;                          // 0..127
  int c0  = (r13 & 63) * 8;                    // 0..504
  int q = row >> 5, rloc = row & 31;
  int mi = rloc >> 4, ar = rloc & 15;
  int kq = c0 >> 7, kr = c0 & 127;
  int ks = kr >> 5, h4 = (kr & 31) >> 3;
  int lane = h4 * 16 + ar;
  const float* src = x + ((size_t)t * BATCH + row) * INDIM + c0;
  f32x4 a = *reinterpret_cast<const f32x4*>(src);
  f32x4 b = *reinterpret_cast<const f32x4*>(src + 4);
  u16x8 u;
  u[0] = f2b(a[0]); u[1] = f2b(a[1]); u[2] = f2b(a[2]); u[3] = f2b(a[3]);
  u[4] = f2b(b[0]); u[5] = f2b(b[1]); u[6] = f2b(b[2]); u[7] = f2b(b[3]);
  size_t dst = ((((((size_t)t * 4 + q) * 4 + kq) * 4 + ks) * 2 + mi) * 64 + lane) * 8;
  *reinterpret_cast<u16x8*>(xs + dst) = u;
}

// ---------------- prepass: build merged weight matrix ----------------
// Bm[dir][jt32][c 0..127][k 0..1535]; c -> G = (c>>5)*1024 + jt32*32 + (c&31)
__global__ void k_build_b(const float* __restrict__ Whh_f, const float* __restrict__ Wih_f,
                          const float* __restrict__ Whh_r, const float* __restrict__ Wih_r,
                          u16* __restrict__ Bm) {
  int blk = blockIdx.x;              // 0..63 = dir*32 + jt32
  int dir = blk >> 5, jt = blk & 31;
  const float* Whh = dir ? Whh_r : Whh_f;
  const float* Wih = dir ? Wih_r : Wih_f;
  u16* dst = Bm + (size_t)blk * 128 * KTOT;
  for (int c = 0; c < 128; c++) {
    int G = (c >> 5) * HDIM + jt * 32 + (c & 31);
    for (int k = threadIdx.x; k < KTOT; k += 256) {
      float v = (k < HDIM) ? Whh[(size_t)G * HDIM + k] : Wih[(size_t)G * INDIM + (k - HDIM)];
      dst[c * KTOT + k] = f2b(v);
    }
  }
}

// ---------------- prepass: init roll slot 0 (SWIZZLED), bias, flags ----------
__global__ void k_init(const float* __restrict__ h0f, const float* __restrict__ h0r,
                       const float* __restrict__ bihf, const float* __restrict__ bhhf,
                       const float* __restrict__ bihr, const float* __restrict__ bhhr,
                       u16* __restrict__ hroll, float* __restrict__ bias,
                       unsigned* __restrict__ flags) {
  int i = blockIdx.x * 256 + threadIdx.x;
  if (i < 2 * BATCH * HDIM) {
    int dir = i / (BATCH * HDIM);
    int rem = i - dir * BATCH * HDIM;
    int r = rem / HDIM, c = rem - r * HDIM;
    const float* h0 = dir ? h0r : h0f;
    char* hb = (char*)hroll;
    *(u16*)(hb + ((size_t)dir * BATCH + r) * 2048 + ((2 * c) ^ ((r & 7) << 4))) =
        f2b(h0[rem]);
  }
  if (i < 2 * GDIM) {
    int dir = i / GDIM, g = i - dir * GDIM;
    bias[i] = dir ? (bihr[g] + bhhr[g]) : (bihf[g] + bhhf[g]);
  }
  if (i < 512) flags[i] = 0;
}

// ---------------- persistent bidirectional LSTM ----------------
// grid 256 x 512. Chain = (dir, batch-quarter) = one per XCD (wg&7), 32 WGs.
// WG = M=32 rows x N=128 gate cols x K=1536. 8 waves = 4 K-split x 2 N-split.
// All weights (bh 64 + bx 32 VGPR) persistent in registers. h staged 64KB via
// global_load_lds from pre-swizzled roll; x loaded fragment-ordered (coalesced)
// into regs before the poll, x-MFMAs overlap the h-stage flight.
__global__ __launch_bounds__(512, 2) void k_lstm(
    const u16* __restrict__ xs, const u16* __restrict__ Bm,
    u16* __restrict__ hroll,
    const float* __restrict__ bias, unsigned* __restrict__ flags,
    const float* __restrict__ c0f, const float* __restrict__ c0r,
    float* __restrict__ out) {
  __shared__ float ldsf[34816];   // 139264B: [0,64K) h-stage | [64K,+73728) partials
  char* ldsc = reinterpret_cast<char*>(ldsf);
  float* ldsP = ldsf + 16384;

  // Invalidate stale L1/L2 lines from a previous graph replay.
  __builtin_amdgcn_fence(__ATOMIC_ACQUIRE, "agent");

  const int wg   = blockIdx.x;
  const int grp  = wg & 7;                     // chain, one per XCD
  const int dir  = grp >> 2, q = grp & 3;
  const int jt32 = wg >> 3;                    // 0..31
  const int tid  = threadIdx.x;
  const int w = tid >> 6, lane = tid & 63;
  const int kq = w >> 1, nh = w & 1;           // 4-way K x 2-way N
  const int h4 = lane >> 4, kk = h4 * 8;
  const int ar = lane & 15;

  // ---- persistent weight fragments (h-part and x-part) ----
  const u16* bsrc = Bm + (size_t)(dir * 32 + jt32) * 128 * KTOT;
  bf16x8 bh[8][4], bx[4][4];
#pragma unroll
  for (int ks = 0; ks < 8; ks++)
#pragma unroll
    for (int ni = 0; ni < 4; ni++)
      bh[ks][ni] = *reinterpret_cast<const bf16x8*>(
          bsrc + (size_t)(nh * 64 + ni * 16 + ar) * KTOT + 256 * kq + 32 * ks + kk);
#pragma unroll
  for (int ks = 0; ks < 4; ks++)
#pragma unroll
    for (int ni = 0; ni < 4; ni++)
      bx[ks][ni] = *reinterpret_cast<const bf16x8*>(
          bsrc + (size_t)(nh * 64 + ni * 16 + ar) * KTOT + HDIM + 128 * kq + 32 * ks + kk);

  // ---- gating thread mapping: 1 row x 2 adjacent h-cols ----
  const int rrow = tid & 31;            // local row (also bank-friendly reduce)
  const int jl0  = 2 * (tid >> 5);      // 0..30 even
  const int row0 = q * 32 + rrow;       // global batch row
  const int jg0  = jt32 * 32 + jl0;     // global h column (even)
  const float* c0 = dir ? c0r : c0f;
  float2 cc = *reinterpret_cast<const float2*>(c0 + (size_t)row0 * HDIM + jg0);
  float cst0 = cc.x, cst1 = cc.y;
  const float2 b_i = *reinterpret_cast<const float2*>(bias + dir * GDIM + 0 * HDIM + jg0);
  const float2 b_f = *reinterpret_cast<const float2*>(bias + dir * GDIM + 1 * HDIM + jg0);
  const float2 b_g = *reinterpret_cast<const float2*>(bias + dir * GDIM + 2 * HDIM + jg0);
  const float2 b_o = *reinterpret_cast<const float2*>(bias + dir * GDIM + 3 * HDIM + jg0);

  const unsigned* fpA = flags + grp * 32 + (lane & 31);  // all 32 producers

#pragma unroll 1
  for (int s = 0; s < T_STEPS; s++) {
    const int t = dir ? (T_STEPS - 1 - s) : s;

    // ---- x fragment loads (coalesced 1KB bursts), issued before the wait ----
    bf16x8 ax[4][2];
    {
      const u16* xb = xs + ((((size_t)t * 4 + q) * 4 + kq) * 4) * 2 * 512;
#pragma unroll
      for (int ks = 0; ks < 4; ks++)
#pragma unroll
        for (int mi = 0; mi < 2; mi++)
          ax[ks][mi] = *reinterpret_cast<const bf16x8*>(
              xb + ((size_t)(ks * 2 + mi) * 64 + lane) * 8);
    }

    // ---- wait for all 32 producers of this chain ----
    if (s > 0) {
      while (true) {
        unsigned f = __hip_atomic_load(fpA, __ATOMIC_RELAXED, __HIP_MEMORY_SCOPE_AGENT);
        if (__all((int)(f >= (unsigned)s))) break;
        __builtin_amdgcn_s_sleep(1);
      }
      __builtin_amdgcn_sched_barrier(0);   // keep glds below the wait
    }

    // ---- stage h tile (64KB, pre-swizzled bytes, linear copy) ----
    {
      const char* hRd = (const char*)hroll + ((size_t)s * 2 + dir) * (BATCH * 2048)
                        + (size_t)q * 32 * 2048;
      unsigned off = (unsigned)tid * 16;
#pragma unroll
      for (int i = 0; i < 8; i++)
        glds16(hRd + off + i * 8192, ldsc + off + i * 8192);
    }
    __builtin_amdgcn_sched_barrier(0);   // keep x-MFMAs below glds issue

    // ---- x MFMAs overlap the glds flight ----
    f32x4 acc[2][4];
#pragma unroll
    for (int mi = 0; mi < 2; mi++)
#pragma unroll
      for (int ni = 0; ni < 4; ni++) acc[mi][ni] = f32x4{0.f, 0.f, 0.f, 0.f};
#pragma unroll
    for (int ks = 0; ks < 4; ks++)
#pragma unroll
      for (int mi = 0; mi < 2; mi++)
#pragma unroll
        for (int ni = 0; ni < 4; ni++)
          acc[mi][ni] = __builtin_amdgcn_mfma_f32_16x16x32_bf16(ax[ks][mi], bx[ks][ni], acc[mi][ni], 0, 0, 0);

    __syncthreads();   // drains glds; h tile resident in LDS

    // ---- h phase: swizzled ds_read_b128 + MFMA ----
#pragma unroll
    for (int ks = 0; ks < 8; ks++) {
      bf16x8 af[2];
#pragma unroll
      for (int mi = 0; mi < 2; mi++) {
        unsigned row = 16 * mi + ar;
        unsigned cb = (256 * kq + 32 * ks + kk) * 2;
        af[mi] = *reinterpret_cast<const bf16x8*>(
            ldsc + row * 2048 + (cb ^ ((row & 7) << 4)));
      }
#pragma unroll
      for (int mi = 0; mi < 2; mi++)
#pragma unroll
        for (int ni = 0; ni < 4; ni++)
          acc[mi][ni] = __builtin_amdgcn_mfma_f32_16x16x32_bf16(af[mi], bh[ks][ni], acc[mi][ni], 0, 0, 0);
    }

    // ---- write per-wave partials: [kq][col 128][36] f32 (disjoint region) ----
    {
      float* pw = ldsP + kq * (128 * 36);
#pragma unroll
      for (int mi = 0; mi < 2; mi++)
#pragma unroll
        for (int ni = 0; ni < 4; ni++) {
          int col = nh * 64 + ni * 16 + ar;
          *reinterpret_cast<f32x4*>(pw + col * 36 + mi * 16 + h4 * 4) = acc[mi][ni];
        }
    }
    __syncthreads();

    // ---- reduce 4 partials + gating (thread: 1 row, 2 h-cols) ----
    float h0v, h1v;
    {
      float gi0 = b_i.x, gi1 = b_i.y, gf0 = b_f.x, gf1 = b_f.y;
      float gg0 = b_g.x, gg1 = b_g.y, go0 = b_o.x, go1 = b_o.y;
#pragma unroll
      for (int k4 = 0; k4 < 4; k4++) {
        const float* p = ldsP + k4 * (128 * 36);
        gi0 += p[(0 * 32 + jl0) * 36 + rrow]; gi1 += p[(0 * 32 + jl0 + 1) * 36 + rrow];
        gf0 += p[(1 * 32 + jl0) * 36 + rrow]; gf1 += p[(1 * 32 + jl0 + 1) * 36 + rrow];
        gg0 += p[(2 * 32 + jl0) * 36 + rrow]; gg1 += p[(2 * 32 + jl0 + 1) * 36 + rrow];
        go0 += p[(3 * 32 + jl0) * 36 + rrow]; go1 += p[(3 * 32 + jl0 + 1) * 36 + rrow];
      }
      float i0 = 1.f / (1.f + __expf(-gi0)), i1 = 1.f / (1.f + __expf(-gi1));
      float f0 = 1.f / (1.f + __expf(-gf0)), f1 = 1.f / (1.f + __expf(-gf1));
      float g0 = tanhf(gg0), g1 = tanhf(gg1);
      float o0 = 1.f / (1.f + __expf(-go0)), o1 = 1.f / (1.f + __expf(-go1));
      cst0 = f0 * cst0 + i0 * g0;
      cst1 = f1 * cst1 + i1 * g1;
      h0v = o0 * tanhf(cst0);
      h1v = o1 * tanhf(cst1);

      // publish h for step s+1 (SWIZZLED layout, write-through to LLC)
      unsigned hp = (unsigned)f2b(h0v) | ((unsigned)f2b(h1v) << 16);
      char* hb = (char*)hroll + ((size_t)(s + 1) * 2 + dir) * (BATCH * 2048);
      __hip_atomic_store(
          (unsigned*)(hb + (size_t)row0 * 2048 + ((2 * jg0) ^ ((row0 & 7) << 4))),
          hp, __ATOMIC_RELAXED, __HIP_MEMORY_SCOPE_AGENT);
    }

    // ---- release: ack h stores -> all waves done -> post flag ----
    asm volatile("s_waitcnt vmcnt(0)" ::: "memory");
    __syncthreads();
    if (tid == 0)
      __hip_atomic_store(flags + grp * 32 + jt32, (unsigned)(s + 1),
                         __ATOMIC_RELAXED, __HIP_MEMORY_SCOPE_AGENT);

    // ---- y stores AFTER the release (off the critical path) ----
    {
      float2 yv; yv.x = h0v; yv.y = h1v;
      *reinterpret_cast<float2*>(out + ((size_t)t * BATCH + row0) * (2 * HDIM)
                                     + (size_t)dir * HDIM + jg0) = yv;
      if (s == T_STEPS - 1) {
        size_t hid = (size_t)T_STEPS * BATCH * 2 * HDIM;
        size_t base2 = hid + (size_t)dir * 2 * BATCH * HDIM;
        *reinterpret_cast<float2*>(out + base2 + (size_t)row0 * HDIM + jg0) = yv;
        float2 cv; cv.x = cst0; cv.y = cst1;
        *reinterpret_cast<float2*>(out + base2 + (size_t)BATCH * HDIM
                                       + (size_t)row0 * HDIM + jg0) = cv;
      }
    }
  }
}

extern "C" void kernel_launch(void* const* d_in, const int* in_sizes, int n_in,
                              void* d_out, int out_size, void* d_ws, size_t ws_size,
                              hipStream_t stream) {
  const float* x     = (const float*)d_in[0];
  const float* h0f   = (const float*)d_in[1];
  const float* c0f   = (const float*)d_in[2];
  const float* h0r   = (const float*)d_in[3];
  const float* c0r   = (const float*)d_in[4];
  const float* Wih_f = (const float*)d_in[5];
  const float* Whh_f = (const float*)d_in[6];
  const float* bih_f = (const float*)d_in[7];
  const float* bhh_f = (const float*)d_in[8];
  const float* Wih_r = (const float*)d_in[9];
  const float* Whh_r = (const float*)d_in[10];
  const float* bih_r = (const float*)d_in[11];
  const float* bhh_r = (const float*)d_in[12];
  float* out = (float*)d_out;
  char* ws = (char*)d_ws;

  if (ws_size < WS_NEED) return;

  u16* xsf        = (u16*)(ws + OFF_XBF);
  u16* Bm         = (u16*)(ws + OFF_BM);
  float* bias     = (float*)(ws + OFF_BIAS);
  unsigned* flags = (unsigned*)(ws + OFF_CNT);
  u16* hroll      = (u16*)(ws + OFF_ROLL);

  k_cast_x<<<8192, 256, 0, stream>>>(x, xsf);
  k_build_b<<<64, 256, 0, stream>>>(Whh_f, Wih_f, Whh_r, Wih_r, Bm);
  k_init<<<1024, 256, 0, stream>>>(h0f, h0r, bih_f, bhh_f, bih_r, bhh_r,
                                   hroll, bias, flags);
  k_lstm<<<256, 512, 0, stream>>>(xsf, Bm, hroll, bias, flags, c0f, c0r, out);
}